// Round 1
// baseline (226.795 us; speedup 1.0000x reference)
//
#include <hip/hip_runtime.h>

// B=4096, D=64, DM=256, K=32, KA=16, S=50
#define B_N 4096
#define TB 4
#define SQUARINGS 8

// ---- workspace layout (float offsets); ~558 KB ----
#define OFF_W5T  0        // 5 x [256 j][64 k] transposed folded mats: q,klat,vlat,kcode,vcode
#define OFF_B5   81920    // 5 x [256]
#define OFF_KALL 83200    // [48][256] rows 0..15 achart@Wk, 16..47 chart@Wk
#define OFF_VALL 95488    // [48][256] @Wv
#define OFF_ANC  107776   // [48][64] anchors (achart then chart)
#define OFF_M    110848   // [256 k][64 d]  Wo @ form_W
#define OFF_G    127232   // [64][64] form_W^T form_W
#define OFF_RS   131328   // 1/sigma (+pad)
#define OFF_A    131392   // [4096] sigma-scaled part
#define OFF_Bc   135488   // [4096] sigma-free part

// ---- k2 LDS layout (floats), TB=4 ----
#define S_ZS    0         // [4][68]
#define S_AZS   272
#define S_ACZS  544
#define S_RWS   816       // [4][36]
#define S_ARWS  960       // [4][20]
#define S_QFP   1040      // [4][260]  q, later feat_pre
#define S_SW    2080      // [4][52]
#define S_RED   2288      // [4][16]
#define S_MST   2352      // [64][68] M chunk stage -> ends 6704
// sigma branch (block 1024) overlays: HA=sm[0..4351], HB=sm[4352..8703], scalars/vec 8704..8771
#define SIG_HB  4352
#define SIG_SC  8704
#define SIG_V   8708
#define SMEM_K2 8772      // 35.1 KB -> 4 blocks/CU

// ===================== K1: weight folds, 2005 light blocks =====================
__global__ __launch_bounds__(256)
void k1_fold(const float* __restrict__ chart_emb, const float* __restrict__ a_chart_emb,
             const float* __restrict__ zW, const float* __restrict__ zb,
             const float* __restrict__ latW, const float* __restrict__ latb,
             const float* __restrict__ codeW, const float* __restrict__ codeb,
             const float* __restrict__ Wq, const float* __restrict__ Wk,
             const float* __restrict__ Wv, const float* __restrict__ Wo,
             const float* __restrict__ fW, const float* __restrict__ ach_anchor,
             const float* __restrict__ ch_anchor, float* __restrict__ ws) {
  __shared__ float red[256];
  const int t = threadIdx.x;
  const int b = blockIdx.x;

  if (b == 2004) {   // anchor copy [48][64]
    for (int e = t; e < 3072; e += 256) {
      int s = e >> 6, d = e & 63;
      ws[OFF_ANC + e] = (s < 16) ? ach_anchor[s * 64 + d] : ch_anchor[(s - 16) * 64 + d];
    }
    return;
  }

  const float* Arow; const float* Bm;
  int astride = 1, bstride = 256, jbase = 0, dstBase, dstStride = 1;
  if (b < 1300) {                       // W5T + biases
    int u = b / 260, r = b - u * 260;
    int i = r >> 2, jc = r & 3; jbase = jc * 64;
    const float* Amat = (u == 0) ? zW : (u <= 2 ? latW : codeW);
    const float* bias = (u == 0) ? zb : (u <= 2 ? latb : codeb);
    Bm = (u == 0) ? Wq : ((u == 1 || u == 3) ? Wk : Wv);
    if (i < 64) {
      Arow = Amat + i * 256;
      dstBase = OFF_W5T + u * 16384 + jbase * 64 + i;
      dstStride = 64;
    } else {
      Arow = bias;
      dstBase = OFF_B5 + u * 256 + jbase;
    }
  } else if (b < 1684) {                // KALL/VALL
    int rr = b - 1300; int row = rr >> 2, jc = rr & 3; jbase = jc * 64;
    int s = (row < 48) ? row : row - 48;
    Bm = (row < 48) ? Wk : Wv;
    Arow = (s < 16) ? (a_chart_emb + s * 256) : (chart_emb + (s - 16) * 256);
    dstBase = OFF_KALL + row * 256 + jbase;
  } else if (b < 1940) {                // M
    int i = b - 1684;
    Arow = Wo + i * 256; Bm = fW; bstride = 64;
    dstBase = OFF_M + i * 64;
  } else {                              // G
    int i = b - 1940;
    Arow = fW + i; astride = 64; Bm = fW; bstride = 64;
    dstBase = OFF_G + i * 64;
  }

  const int j = t & 63, ks = t >> 6;
  const float* ap = Arow + (ks * 64) * astride;
  const float* bp = Bm + (ks * 64) * bstride + jbase + j;
  float a0 = 0.f, a1 = 0.f, a2 = 0.f, a3 = 0.f;
  #pragma unroll 4
  for (int k = 0; k < 64; k += 4) {
    a0 += ap[(k + 0) * astride] * bp[(k + 0) * bstride];
    a1 += ap[(k + 1) * astride] * bp[(k + 1) * bstride];
    a2 += ap[(k + 2) * astride] * bp[(k + 2) * bstride];
    a3 += ap[(k + 3) * astride] * bp[(k + 3) * bstride];
  }
  red[t] = (a0 + a1) + (a2 + a3);
  __syncthreads();
  if (t < 64) {
    float v = red[t] + red[64 + t] + red[128 + t] + red[192 + t];
    ws[dstBase + t * dstStride] = v;
  }
}

// one matvec at a time: r[bi] = bias[t] + sum_k x[bi][k] * W5T[u][t][k]
__device__ __forceinline__ void mv(const float* __restrict__ ws, int u,
                                   const float* xs, int t, float* r) {
  const float* w = ws + OFF_W5T + u * 16384 + t * 64;
  float bq = ws[OFF_B5 + u * 256 + t];
  #pragma unroll
  for (int bi = 0; bi < TB; ++bi) r[bi] = bq;
  #pragma unroll 4
  for (int k4 = 0; k4 < 16; ++k4) {
    float4 w4 = *(const float4*)(w + k4 * 4);
    #pragma unroll
    for (int bi = 0; bi < TB; ++bi) {
      float4 x4 = *(const float4*)&xs[bi * 68 + k4 * 4];
      r[bi] += x4.x * w4.x + x4.y * w4.y + x4.z * w4.z + x4.w * w4.w;
    }
  }
}

// ===================== K2: everything per-batch (+ sigma block) =====================
__global__ __launch_bounds__(256, 4)
void k2_main(const float* __restrict__ z, const float* __restrict__ rw,
             const float* __restrict__ az, const float* __restrict__ arw,
             const float* __restrict__ acz, const float* __restrict__ ctrl,
             const float* __restrict__ ecov, const float* __restrict__ fb,
             float* __restrict__ ws) {
  __shared__ __align__(16) float sm[SMEM_K2];
  const int t = threadIdx.x;
  const int wv = t >> 6, ln = t & 63;

  if (blockIdx.x == 1024) {
    // ---------- sigma: 8 trace-normalized squarings of G, 2 LDS buffers, Rayleigh on global G ----------
    float* HA = sm;
    float* HB = sm + SIG_HB;
    {
      float tv = (t < 64) ? ws[OFF_G + t * 65] : 0.f;
      #pragma unroll
      for (int m = 32; m >= 1; m >>= 1) tv += __shfl_xor(tv, m, 64);
      if (t == 0) sm[SIG_SC] = (tv > 0.f) ? 1.f / tv : 0.f;
    }
    __syncthreads();
    {
      float inv0 = sm[SIG_SC];
      for (int e = t; e < 4096; e += 256) {
        int i = e >> 6, j = e & 63;
        HA[i * 68 + j] = ws[OFF_G + e] * inv0;
      }
    }
    __syncthreads();
    for (int it = 0; it < SQUARINGS; ++it) {
      float* src = (it & 1) ? HB : HA;
      float* dst = (it & 1) ? HA : HB;
      float acc16[16];
      #pragma unroll
      for (int r = 0; r < 16; ++r) acc16[r] = 0.f;
      for (int half = 0; half < 2; ++half) {        // 32-wide column cache halves
        float cb[32];
        #pragma unroll
        for (int k = 0; k < 32; ++k) cb[k] = src[(half * 32 + k) * 68 + ln];
        #pragma unroll
        for (int r = 0; r < 16; ++r) {
          int i = r * 4 + wv;
          float a = 0.f;
          #pragma unroll
          for (int k4 = 0; k4 < 8; ++k4) {
            float4 a4 = *(const float4*)&src[i * 68 + half * 32 + k4 * 4];
            a += a4.x * cb[k4 * 4] + a4.y * cb[k4 * 4 + 1] + a4.z * cb[k4 * 4 + 2] + a4.w * cb[k4 * 4 + 3];
          }
          acc16[r] += a;
        }
      }
      #pragma unroll
      for (int r = 0; r < 16; ++r) dst[(r * 4 + wv) * 68 + ln] = acc16[r];
      __syncthreads();
      {
        float tv = (t < 64) ? dst[t * 68 + t] : 0.f;
        #pragma unroll
        for (int m = 32; m >= 1; m >>= 1) tv += __shfl_xor(tv, m, 64);
        if (t == 0) sm[SIG_SC] = (tv > 0.f) ? 1.f / tv : 0.f;
      }
      __syncthreads();
      {
        float sc = sm[SIG_SC];
        #pragma unroll
        for (int r = 0; r < 16; ++r) dst[(r * 4 + wv) * 68 + ln] *= sc;
      }
      __syncthreads();
    }
    float* H = (SQUARINGS & 1) ? HB : HA;
    if (t < 64) {
      float cn = 0.f;
      for (int i = 0; i < 64; ++i) { float h = H[i * 68 + t]; cn += h * h; }
      float bv = cn; int bj = t;
      #pragma unroll
      for (int m = 32; m >= 1; m >>= 1) {
        float ov = __shfl_xor(bv, m, 64);
        int   oj = __shfl_xor(bj, m, 64);
        if (ov > bv || (ov == bv && oj < bj)) { bv = ov; bj = oj; }
      }
      if (t == 0) sm[SIG_SC + 1] = (float)bj;
    }
    __syncthreads();
    {
      int jmax = (int)sm[SIG_SC + 1];
      if (t < 64) sm[SIG_V + t] = H[t * 68 + jmax];
    }
    __syncthreads();
    if (t < 64) {
      float vi = sm[SIG_V + t];
      float y = 0.f;
      #pragma unroll 4
      for (int k = 0; k < 64; ++k) y += ws[OFF_G + t * 64 + k] * sm[SIG_V + k];
      float num = vi * y, den = vi * vi;
      #pragma unroll
      for (int m = 32; m >= 1; m >>= 1) {
        num += __shfl_xor(num, m, 64);
        den += __shfl_xor(den, m, 64);
      }
      if (t == 0) {
        float lam = (den > 1e-37f) ? num / den : 0.f;
        lam = fmaxf(lam, 0.f);
        float sg = sqrtf(lam);
        ws[OFF_RS] = 1.f / fmaxf(sg, 1e-8f);
      }
    }
    return;
  }

  // ---------- main: 1024 blocks x 4 batches ----------
  const int b0 = blockIdx.x * TB;
  {
    int bb = b0 + wv;                       // one row per wave, coalesced 256B
    sm[S_ZS   + wv * 68 + ln] = z[bb * 64 + ln];
    sm[S_AZS  + wv * 68 + ln] = az[bb * 64 + ln];
    sm[S_ACZS + wv * 68 + ln] = acz[bb * 64 + ln];
  }
  if (t < 128) { int bi = t >> 5, d = t & 31; sm[S_RWS + bi * 36 + d] = rw[(b0 + bi) * 32 + d]; }
  if (t < 64)  { int bi = t >> 4, d = t & 15; sm[S_ARWS + bi * 20 + d] = arw[(b0 + bi) * 16 + d]; }
  __syncthreads();

  // --- q (kept live briefly), k_lat / k_code consumed immediately ---
  float qr[TB];
  mv(ws, 0, sm + S_ZS, t, qr);
  #pragma unroll
  for (int bi = 0; bi < TB; ++bi) sm[S_QFP + bi * 260 + t] = qr[bi];
  {
    float kr[TB];
    mv(ws, 1, sm + S_AZS, t, kr);
    #pragma unroll
    for (int bi = 0; bi < TB; ++bi) {
      float p = qr[bi] * kr[bi];
      #pragma unroll
      for (int m = 32; m >= 1; m >>= 1) p += __shfl_xor(p, m, 64);
      if (ln == 0) sm[S_RED + bi * 16 + wv] = p;
    }
  }
  {
    float kr[TB];
    mv(ws, 3, sm + S_ACZS, t, kr);
    #pragma unroll
    for (int bi = 0; bi < TB; ++bi) {
      float p = qr[bi] * kr[bi];
      #pragma unroll
      for (int m = 32; m >= 1; m >>= 1) p += __shfl_xor(p, m, 64);
      if (ln == 0) sm[S_RED + bi * 16 + 4 + wv] = p;
    }
  }
  {
    // lat/code latent distances: wave wv handles batch wv (was: wave 0 serial over all batches)
    float a = sm[S_ZS + wv * 68 + ln] - sm[S_AZS + wv * 68 + ln];
    float c = sm[S_ZS + wv * 68 + ln] - sm[S_ACZS + wv * 68 + ln];
    float dL = a * a, dC = c * c;
    #pragma unroll
    for (int m = 32; m >= 1; m >>= 1) { dL += __shfl_xor(dL, m, 64); dC += __shfl_xor(dC, m, 64); }
    if (ln == 0) { sm[S_RED + wv * 16 + 8] = dL; sm[S_RED + wv * 16 + 9] = dC; }
  }
  // --- v_lat / v_code, kept in regs until feat_pre ---
  float vlr[TB], vcr[TB];
  mv(ws, 2, sm + S_AZS, t, vlr);
  mv(ws, 4, sm + S_ACZS, t, vcr);
  __syncthreads();

  if (t < TB) {
    float pL = sm[S_RED + t * 16 + 0] + sm[S_RED + t * 16 + 1] + sm[S_RED + t * 16 + 2] + sm[S_RED + t * 16 + 3];
    float pC = sm[S_RED + t * 16 + 4] + sm[S_RED + t * 16 + 5] + sm[S_RED + t * 16 + 6] + sm[S_RED + t * 16 + 7];
    sm[S_SW + t * 52 + 48] = pL * 0.0625f - sm[S_RED + t * 16 + 8];
    sm[S_SW + t * 52 + 49] = pC * 0.0625f - sm[S_RED + t * 16 + 9];
  }

  // chart scores: 192 tasks (s,bi), one per thread
  for (int jb = t; jb < 48 * TB; jb += 256) {
    int s = jb >> 2, bi = jb & 3;
    const float* krow = ws + OFF_KALL + s * 256;
    float dot = 0.f;
    #pragma unroll 4
    for (int k4 = 0; k4 < 64; ++k4) {
      float4 q4 = *(const float4*)&sm[S_QFP + bi * 260 + k4 * 4];
      float4 kk = *(const float4*)(krow + k4 * 4);
      dot += q4.x * kk.x + q4.y * kk.y + q4.z * kk.z + q4.w * kk.w;
    }
    const float* anc = ws + OFF_ANC + s * 64;
    float d2 = 0.f;
    #pragma unroll 4
    for (int k4 = 0; k4 < 16; ++k4) {
      float4 z4 = *(const float4*)&sm[S_ZS + bi * 68 + k4 * 4];
      float4 a4 = *(const float4*)(anc + k4 * 4);
      float d0 = z4.x - a4.x, d1 = z4.y - a4.y, dd = z4.z - a4.z, d3 = z4.w - a4.w;
      d2 += d0 * d0 + d1 * d1 + dd * dd + d3 * d3;
    }
    float rwv = (s < 16) ? sm[S_ARWS + bi * 20 + s] : sm[S_RWS + bi * 36 + (s - 16)];
    sm[S_SW + bi * 52 + s] = rwv * dot * 0.0625f - d2;
  }
  __syncthreads();

  // softmax + fold routing weights: wave-parallel, wave wv owns batch wv
  {
    float* swr = &sm[S_SW + wv * 52];
    float scv = (ln < 50) ? swr[ln] : -1e30f;
    float mx = scv;
    #pragma unroll
    for (int m = 32; m >= 1; m >>= 1) mx = fmaxf(mx, __shfl_xor(mx, m, 64));
    float ev = (ln < 50) ? __expf(scv - mx) : 0.f;
    float sum = ev;
    #pragma unroll
    for (int m = 32; m >= 1; m >>= 1) sum += __shfl_xor(sum, m, 64);
    float inv = 1.f / sum;
    float fold = 1.f;
    if (ln < 16) fold = sm[S_ARWS + wv * 20 + ln];
    else if (ln < 48) fold = sm[S_RWS + wv * 36 + (ln - 16)];
    if (ln < 50) swr[ln] = ev * inv * fold;
  }
  __syncthreads();

  // feat_pre column t for 4 batches -> S_QFP (overwrites q; last q-read was before the softmax barrier)
  {
    float acc[TB];
    #pragma unroll
    for (int bi = 0; bi < TB; ++bi)
      acc[bi] = sm[S_SW + bi * 52 + 48] * vlr[bi] + sm[S_SW + bi * 52 + 49] * vcr[bi];
    for (int sc = 0; sc < 12; ++sc) {
      float v0 = ws[OFF_VALL + (sc * 4 + 0) * 256 + t];
      float v1 = ws[OFF_VALL + (sc * 4 + 1) * 256 + t];
      float v2 = ws[OFF_VALL + (sc * 4 + 2) * 256 + t];
      float v3 = ws[OFF_VALL + (sc * 4 + 3) * 256 + t];
      #pragma unroll
      for (int bi = 0; bi < TB; ++bi) {
        float4 w4 = *(const float4*)&sm[S_SW + bi * 52 + sc * 4];
        acc[bi] += w4.x * v0 + w4.y * v1 + w4.z * v2 + w4.w * v3;
      }
    }
    #pragma unroll
    for (int bi = 0; bi < TB; ++bi) sm[S_QFP + bi * 260 + t] = acc[bi];
  }

  // g = feat_pre @ M (M staged in 64-row LDS chunks); 1 output/thread: batch wv, dim ln
  float g0 = 0.f;
  const int d = ln;
  for (int tc = 0; tc < 4; ++tc) {
    __syncthreads();   // tc=0: also the S_QFP write->read barrier
    for (int e = t * 4; e < 4096; e += 1024) {
      int kr = e >> 6, dd = e & 63;
      *(float4*)&sm[S_MST + kr * 68 + dd] = *(const float4*)(ws + OFF_M + (tc * 64 + kr) * 64 + dd);
    }
    __syncthreads();
    #pragma unroll 4
    for (int k4 = 0; k4 < 16; ++k4) {
      float m0 = sm[S_MST + (k4 * 4 + 0) * 68 + d];
      float m1 = sm[S_MST + (k4 * 4 + 1) * 68 + d];
      float m2 = sm[S_MST + (k4 * 4 + 2) * 68 + d];
      float m3 = sm[S_MST + (k4 * 4 + 3) * 68 + d];
      float4 f0 = *(const float4*)&sm[S_QFP + wv * 260 + tc * 64 + k4 * 4];  // wave-uniform -> LDS broadcast
      g0 += f0.x * m0 + f0.y * m1 + f0.z * m2 + f0.w * m3;
    }
  }

  // epilogue: per-batch projections -> A (needs 1/sigma), B (sigma-free)
  {
    float fbv = fb[d];
    int bb = b0 + wv;
    float c = ctrl[bb * 64 + d];
    float e = ecov[bb * 64 + d];
    float gc = g0 * c, ge = g0 * e, ec = e * c, ee = e * e, fc = fbv * c, fe = fbv * e;
    #pragma unroll
    for (int m = 32; m >= 1; m >>= 1) {
      gc += __shfl_xor(gc, m, 64);
      ge += __shfl_xor(ge, m, 64);
      ec += __shfl_xor(ec, m, 64);
      ee += __shfl_xor(ee, m, 64);
      fc += __shfl_xor(fc, m, 64);
      fe += __shfl_xor(fe, m, 64);
    }
    if (ln == 0) {
      float A, Bv;
      if (ee > 1e-8f) { float r = ec / ee; A = gc - ge * r; Bv = fc - fe * r; }
      else { A = gc; Bv = fc; }
      ws[OFF_A  + bb] = A;
      ws[OFF_Bc + bb] = Bv;
    }
  }
}

// ===================== K3: apply 1/sigma =====================
__global__ __launch_bounds__(256)
void k3_out(const float* __restrict__ ws, float* __restrict__ out) {
  int b = blockIdx.x * 256 + threadIdx.x;
  float rs = ws[OFF_RS];
  out[b] = ws[OFF_A + b] * rs + ws[OFF_Bc + b];
}

extern "C" void kernel_launch(void* const* d_in, const int* in_sizes, int n_in,
                              void* d_out, int out_size, void* d_ws, size_t ws_size,
                              hipStream_t stream) {
  const float* z     = (const float*)d_in[0];
  const float* rw    = (const float*)d_in[1];
  const float* az    = (const float*)d_in[2];
  const float* arw   = (const float*)d_in[3];
  const float* acz   = (const float*)d_in[4];
  const float* ctrl  = (const float*)d_in[5];
  const float* ecov  = (const float*)d_in[6];
  const float* chemb = (const float*)d_in[7];
  const float* chanc = (const float*)d_in[8];
  const float* aemb  = (const float*)d_in[9];
  const float* aanc  = (const float*)d_in[10];
  const float* zW    = (const float*)d_in[11];
  const float* zb    = (const float*)d_in[12];
  const float* latW  = (const float*)d_in[13];
  const float* latb  = (const float*)d_in[14];
  const float* codeW = (const float*)d_in[15];
  const float* codeb = (const float*)d_in[16];
  const float* Wq    = (const float*)d_in[17];
  const float* Wk    = (const float*)d_in[18];
  const float* Wv    = (const float*)d_in[19];
  const float* Wo    = (const float*)d_in[20];
  const float* fW    = (const float*)d_in[21];
  const float* fb    = (const float*)d_in[22];
  float* ws  = (float*)d_ws;
  float* out = (float*)d_out;

  k1_fold<<<2005, 256, 0, stream>>>(chemb, aemb, zW, zb, latW, latb, codeW, codeb,
                                    Wq, Wk, Wv, Wo, fW, aanc, chanc, ws);
  k2_main<<<1025, 256, 0, stream>>>(z, rw, az, arw, acz, ctrl, ecov, fb, ws);
  k3_out<<<16, 256, 0, stream>>>(ws, out);
}

// Round 2
// 226.452 us; speedup vs baseline: 1.0015x; 1.0015x over previous
//
#include <hip/hip_runtime.h>

// B=4096, D=64, DM=256, K=32, KA=16, S=50
#define TB 8
#define SQUARINGS 8

// ---- workspace layout (float offsets); ~559 KB ----
#define OFF_W5    0        // 5 x [64 k][256 j] folded mats (natural layout): q,klat,vlat,kcode,vcode
#define OFF_B5    81920    // 5 x [256]
#define OFF_KALLT 83200    // [256 k][48 s]  (achart rows 0..15, chart 16..47) @Wk, transposed
#define OFF_VALL  95488    // [48 s][256 j] @Wv
#define OFF_ANCT  107776   // [64 d][48 s] anchors transposed
#define OFF_ANCN  110848   // [64] |anchor_s|^2 (48 used)
#define OFF_M     110912   // [256 k][64 d]  Wo @ form_W
#define OFF_G     127296   // [64][64] form_W^T form_W
#define OFF_RS    131392   // 1/sigma (+pad)
#define OFF_A     131456   // [4096] sigma-scaled part
#define OFF_Bc    135552   // [4096] sigma-free part  (end 139648)

// ---- k2 LDS layout (floats), TB=8 ----
#define S_ZS    0         // [8][68]
#define S_AZS   544
#define S_ACZS  1088
#define S_RWS   1632      // [8][36]
#define S_ARWS  1920      // [8][20]
#define S_QFP   2080      // [8][260]  q, later feat_pre
#define S_SW    4160      // [8][52]
#define S_RED   4576      // [8][16]
#define S_MST   4704      // [64][68] M chunk stage -> ends 9056
// sigma overlay: HA=sm[0..4351], HB=sm[4352..8703], scalars 8704..8771
#define SIG_HB  4352
#define SIG_SC  8704
#define SIG_V   8708
#define SMEM_K2 9056      // 36.2 KB

// ===================== K1: weight folds, 78 fat blocks =====================
// b 0..39  : W5 u-mat tiles (u=b>>3, 8 rows each)
// b 40..45 : KALLT tiles (8 s-rows each, transposed store)
// b 46..51 : VALL tiles  (8 s-rows each)
// b 52..59 : M tiles (32 rows each)
// b 60..75 : G tiles (4 i-rows each)
// b 76     : B5 (all 5 folded biases)
// b 77     : ANCT + ANCN
__global__ __launch_bounds__(256)
void k1_fold(const float* __restrict__ chart_emb, const float* __restrict__ a_chart_emb,
             const float* __restrict__ zW, const float* __restrict__ zb,
             const float* __restrict__ latW, const float* __restrict__ latb,
             const float* __restrict__ codeW, const float* __restrict__ codeb,
             const float* __restrict__ Wq, const float* __restrict__ Wk,
             const float* __restrict__ Wv, const float* __restrict__ Wo,
             const float* __restrict__ fW, const float* __restrict__ ach_anchor,
             const float* __restrict__ ch_anchor, float* __restrict__ ws) {
  __shared__ __align__(16) float As[8192];
  const int t = threadIdx.x;
  const int b = blockIdx.x;

  if (b < 52) {
    // generic: C[8 rows][256 j], K=256, A staged in LDS, B coalesced from global
    const float* Arows; const float* Bm;
    int mode = 0, i0, dst = 0;
    if (b < 40) {
      int u = b >> 3, r = b & 7; i0 = r * 8;
      const float* Amat = (u == 0) ? zW : (u <= 2 ? latW : codeW);
      Arows = Amat + i0 * 256;
      Bm = (u == 0) ? Wq : ((u == 1 || u == 3) ? Wk : Wv);
      dst = OFF_W5 + u * 16384 + i0 * 256;
    } else if (b < 46) {
      int r = b - 40; i0 = r * 8;
      Arows = (i0 < 16) ? (a_chart_emb + i0 * 256) : (chart_emb + (i0 - 16) * 256);
      Bm = Wk; mode = 1;                      // transposed store into KALLT
    } else {
      int r = b - 46; i0 = r * 8;
      Arows = (i0 < 16) ? (a_chart_emb + i0 * 256) : (chart_emb + (i0 - 16) * 256);
      Bm = Wv;
      dst = OFF_VALL + i0 * 256;
    }
    for (int e = t; e < 2048; e += 256) As[e] = Arows[e];
    __syncthreads();
    float acc[8];
    #pragma unroll
    for (int ii = 0; ii < 8; ++ii) acc[ii] = 0.f;
    #pragma unroll 4
    for (int k4 = 0; k4 < 64; ++k4) {
      float b0 = Bm[(k4 * 4 + 0) * 256 + t];
      float b1 = Bm[(k4 * 4 + 1) * 256 + t];
      float b2 = Bm[(k4 * 4 + 2) * 256 + t];
      float b3 = Bm[(k4 * 4 + 3) * 256 + t];
      #pragma unroll
      for (int ii = 0; ii < 8; ++ii) {
        float4 a4 = *(const float4*)&As[ii * 256 + k4 * 4];
        acc[ii] += a4.x * b0 + a4.y * b1 + a4.z * b2 + a4.w * b3;
      }
    }
    if (mode == 0) {
      #pragma unroll
      for (int ii = 0; ii < 8; ++ii) ws[dst + ii * 256 + t] = acc[ii];
    } else {
      #pragma unroll
      for (int ii = 0; ii < 8; ++ii) ws[OFF_KALLT + t * 48 + i0 + ii] = acc[ii];
    }
    return;
  }

  if (b < 60) {                    // M = Wo @ fW, tile of 32 rows
    int i0 = (b - 52) * 32;
    const int jj = t & 63, q = t >> 6;
    for (int e = t; e < 8192; e += 256) As[e] = Wo[i0 * 256 + e];
    __syncthreads();
    float acc[8];
    #pragma unroll
    for (int m = 0; m < 8; ++m) acc[m] = 0.f;
    #pragma unroll 4
    for (int k4 = 0; k4 < 64; ++k4) {
      float b0 = fW[(k4 * 4 + 0) * 64 + jj];
      float b1 = fW[(k4 * 4 + 1) * 64 + jj];
      float b2 = fW[(k4 * 4 + 2) * 64 + jj];
      float b3 = fW[(k4 * 4 + 3) * 64 + jj];
      #pragma unroll
      for (int m = 0; m < 8; ++m) {
        float4 a4 = *(const float4*)&As[(m * 4 + q) * 256 + k4 * 4];
        acc[m] += a4.x * b0 + a4.y * b1 + a4.z * b2 + a4.w * b3;
      }
    }
    #pragma unroll
    for (int m = 0; m < 8; ++m) ws[OFF_M + (i0 + m * 4 + q) * 64 + jj] = acc[m];
    return;
  }

  if (b < 76) {                    // G = fW^T fW, tile of 4 i-rows
    const int jj = t & 63;
    const int i = (b - 60) * 4 + (t >> 6);
    float acc = 0.f;
    for (int c = 0; c < 4; ++c) {
      __syncthreads();
      for (int e = t * 4; e < 4096; e += 1024)
        *(float4*)&As[e] = *(const float4*)&fW[c * 4096 + e];
      __syncthreads();
      #pragma unroll 4
      for (int k = 0; k < 64; ++k)
        acc += As[k * 64 + i] * As[k * 64 + jj];
    }
    ws[OFF_G + i * 64 + jj] = acc;
    return;
  }

  if (b == 76) {                   // B5: folded biases
    for (int u = 0; u < 5; ++u) {
      const float* bias = (u == 0) ? zb : (u <= 2 ? latb : codeb);
      const float* Bm = (u == 0) ? Wq : ((u == 1 || u == 3) ? Wk : Wv);
      __syncthreads();
      As[t] = bias[t];
      __syncthreads();
      float acc = 0.f;
      #pragma unroll 4
      for (int k = 0; k < 256; ++k) acc += As[k] * Bm[k * 256 + t];
      ws[OFF_B5 + u * 256 + t] = acc;
    }
    return;
  }

  // b == 77: ANCT (transposed anchors) + ANCN (|anchor|^2)
  for (int e = t; e < 3072; e += 256) {
    int s = e >> 6, d = e & 63;
    float v = (s < 16) ? ach_anchor[s * 64 + d] : ch_anchor[(s - 16) * 64 + d];
    ws[OFF_ANCT + d * 48 + s] = v;
  }
  if (t < 64) {
    float n = 0.f;
    if (t < 48) {
      const float* a = (t < 16) ? (ach_anchor + t * 64) : (ch_anchor + (t - 16) * 64);
      for (int d = 0; d < 64; ++d) n += a[d] * a[d];
    }
    ws[OFF_ANCN + t] = n;
  }
}

// coalesced matvec: r[bi] = bias[t] + sum_k x[bi][k] * W5[u][k][t]
// lane ln loads W5[k][wv*64+ln] -> consecutive addresses (4 lines/wave-load)
__device__ __forceinline__ void mv(const float* __restrict__ ws, int u,
                                   const float* xs, int t, float* r) {
  const float* w = ws + OFF_W5 + u * 16384 + t;
  float bq = ws[OFF_B5 + u * 256 + t];
  #pragma unroll
  for (int bi = 0; bi < TB; ++bi) r[bi] = bq;
  #pragma unroll 4
  for (int k4 = 0; k4 < 16; ++k4) {
    float w0 = w[(k4 * 4 + 0) * 256];
    float w1 = w[(k4 * 4 + 1) * 256];
    float w2 = w[(k4 * 4 + 2) * 256];
    float w3 = w[(k4 * 4 + 3) * 256];
    #pragma unroll
    for (int bi = 0; bi < TB; ++bi) {
      float4 x4 = *(const float4*)&xs[bi * 68 + k4 * 4];
      r[bi] += x4.x * w0 + x4.y * w1 + x4.z * w2 + x4.w * w3;
    }
  }
}

// ===================== K2: everything per-batch (+ sigma block) =====================
__global__ __launch_bounds__(256, 4)
void k2_main(const float* __restrict__ z, const float* __restrict__ rw,
             const float* __restrict__ az, const float* __restrict__ arw,
             const float* __restrict__ acz, const float* __restrict__ ctrl,
             const float* __restrict__ ecov, const float* __restrict__ fb,
             float* __restrict__ ws) {
  __shared__ __align__(16) float sm[SMEM_K2];
  const int t = threadIdx.x;
  const int wv = t >> 6, ln = t & 63;

  if (blockIdx.x == 512) {
    // ---------- sigma: 8 trace-normalized squarings of G, Rayleigh on global G ----------
    float* HA = sm;
    float* HB = sm + SIG_HB;
    {
      float tv = (t < 64) ? ws[OFF_G + t * 65] : 0.f;
      #pragma unroll
      for (int m = 32; m >= 1; m >>= 1) tv += __shfl_xor(tv, m, 64);
      if (t == 0) sm[SIG_SC] = (tv > 0.f) ? 1.f / tv : 0.f;
    }
    __syncthreads();
    {
      float inv0 = sm[SIG_SC];
      for (int e = t; e < 4096; e += 256) {
        int i = e >> 6, j = e & 63;
        HA[i * 68 + j] = ws[OFF_G + e] * inv0;
      }
    }
    __syncthreads();
    for (int it = 0; it < SQUARINGS; ++it) {
      float* src = (it & 1) ? HB : HA;
      float* dst = (it & 1) ? HA : HB;
      float acc16[16];
      #pragma unroll
      for (int r = 0; r < 16; ++r) acc16[r] = 0.f;
      for (int half = 0; half < 2; ++half) {
        float cb[32];
        #pragma unroll
        for (int k = 0; k < 32; ++k) cb[k] = src[(half * 32 + k) * 68 + ln];
        #pragma unroll
        for (int r = 0; r < 16; ++r) {
          int i = r * 4 + wv;
          float a = 0.f;
          #pragma unroll
          for (int k4 = 0; k4 < 8; ++k4) {
            float4 a4 = *(const float4*)&src[i * 68 + half * 32 + k4 * 4];
            a += a4.x * cb[k4 * 4] + a4.y * cb[k4 * 4 + 1] + a4.z * cb[k4 * 4 + 2] + a4.w * cb[k4 * 4 + 3];
          }
          acc16[r] += a;
        }
      }
      #pragma unroll
      for (int r = 0; r < 16; ++r) dst[(r * 4 + wv) * 68 + ln] = acc16[r];
      __syncthreads();
      {
        float tv = (t < 64) ? dst[t * 68 + t] : 0.f;
        #pragma unroll
        for (int m = 32; m >= 1; m >>= 1) tv += __shfl_xor(tv, m, 64);
        if (t == 0) sm[SIG_SC] = (tv > 0.f) ? 1.f / tv : 0.f;
      }
      __syncthreads();
      {
        float sc = sm[SIG_SC];
        #pragma unroll
        for (int r = 0; r < 16; ++r) dst[(r * 4 + wv) * 68 + ln] *= sc;
      }
      __syncthreads();
    }
    float* H = (SQUARINGS & 1) ? HB : HA;
    if (t < 64) {
      float cn = 0.f;
      for (int i = 0; i < 64; ++i) { float h = H[i * 68 + t]; cn += h * h; }
      float bv = cn; int bj = t;
      #pragma unroll
      for (int m = 32; m >= 1; m >>= 1) {
        float ov = __shfl_xor(bv, m, 64);
        int   oj = __shfl_xor(bj, m, 64);
        if (ov > bv || (ov == bv && oj < bj)) { bv = ov; bj = oj; }
      }
      if (t == 0) sm[SIG_SC + 1] = (float)bj;
    }
    __syncthreads();
    {
      int jmax = (int)sm[SIG_SC + 1];
      if (t < 64) sm[SIG_V + t] = H[t * 68 + jmax];
    }
    __syncthreads();
    if (t < 64) {
      float vi = sm[SIG_V + t];
      float y = 0.f;
      #pragma unroll 4
      for (int k = 0; k < 64; ++k) y += ws[OFF_G + t * 64 + k] * sm[SIG_V + k];
      float num = vi * y, den = vi * vi;
      #pragma unroll
      for (int m = 32; m >= 1; m >>= 1) {
        num += __shfl_xor(num, m, 64);
        den += __shfl_xor(den, m, 64);
      }
      if (t == 0) {
        float lam = (den > 1e-37f) ? num / den : 0.f;
        lam = fmaxf(lam, 0.f);
        float sg = sqrtf(lam);
        ws[OFF_RS] = 1.f / fmaxf(sg, 1e-8f);
      }
    }
    return;
  }

  // ---------- main: 512 blocks x 8 batches ----------
  const int b0 = blockIdx.x * TB;
  for (int e = t; e < TB * 64; e += 256) {
    int bi = e >> 6, d = e & 63; int bb = b0 + bi;
    sm[S_ZS   + bi * 68 + d] = z[bb * 64 + d];
    sm[S_AZS  + bi * 68 + d] = az[bb * 64 + d];
    sm[S_ACZS + bi * 68 + d] = acz[bb * 64 + d];
  }
  { int bi = t >> 5, d = t & 31; sm[S_RWS + bi * 36 + d] = rw[(b0 + bi) * 32 + d]; }
  if (t < 128) { int bi = t >> 4, d = t & 15; sm[S_ARWS + bi * 20 + d] = arw[(b0 + bi) * 16 + d]; }
  __syncthreads();

  // --- q (kept live briefly), k_lat / k_code consumed immediately ---
  float qr[TB];
  mv(ws, 0, sm + S_ZS, t, qr);
  #pragma unroll
  for (int bi = 0; bi < TB; ++bi) sm[S_QFP + bi * 260 + t] = qr[bi];
  {
    float kr[TB];
    mv(ws, 1, sm + S_AZS, t, kr);
    #pragma unroll
    for (int bi = 0; bi < TB; ++bi) {
      float p = qr[bi] * kr[bi];
      #pragma unroll
      for (int m = 32; m >= 1; m >>= 1) p += __shfl_xor(p, m, 64);
      if (ln == 0) sm[S_RED + bi * 16 + wv] = p;
    }
  }
  {
    float kr[TB];
    mv(ws, 3, sm + S_ACZS, t, kr);
    #pragma unroll
    for (int bi = 0; bi < TB; ++bi) {
      float p = qr[bi] * kr[bi];
      #pragma unroll
      for (int m = 32; m >= 1; m >>= 1) p += __shfl_xor(p, m, 64);
      if (ln == 0) sm[S_RED + bi * 16 + 4 + wv] = p;
    }
  }
  {
    // lat/code latent distances + |z|^2: wave wv owns batches wv and wv+4
    #pragma unroll
    for (int h = 0; h < 2; ++h) {
      int bi = wv + 4 * h;
      float zv = sm[S_ZS + bi * 68 + ln];
      float a = zv - sm[S_AZS + bi * 68 + ln];
      float c = zv - sm[S_ACZS + bi * 68 + ln];
      float dL = a * a, dC = c * c, zz = zv * zv;
      #pragma unroll
      for (int m = 32; m >= 1; m >>= 1) {
        dL += __shfl_xor(dL, m, 64);
        dC += __shfl_xor(dC, m, 64);
        zz += __shfl_xor(zz, m, 64);
      }
      if (ln == 0) {
        sm[S_RED + bi * 16 + 8] = dL;
        sm[S_RED + bi * 16 + 9] = dC;
        sm[S_RED + bi * 16 + 10] = zz;
      }
    }
  }
  // --- v_lat / v_code, kept in regs until feat_pre ---
  float vlr[TB], vcr[TB];
  mv(ws, 2, sm + S_AZS, t, vlr);
  mv(ws, 4, sm + S_ACZS, t, vcr);
  __syncthreads();

  if (t < TB) {
    float pL = sm[S_RED + t * 16 + 0] + sm[S_RED + t * 16 + 1] + sm[S_RED + t * 16 + 2] + sm[S_RED + t * 16 + 3];
    float pC = sm[S_RED + t * 16 + 4] + sm[S_RED + t * 16 + 5] + sm[S_RED + t * 16 + 6] + sm[S_RED + t * 16 + 7];
    sm[S_SW + t * 52 + 48] = pL * 0.0625f - sm[S_RED + t * 16 + 8];
    sm[S_SW + t * 52 + 49] = pC * 0.0625f - sm[S_RED + t * 16 + 9];
  }

  // chart scores: wave wv handles batches {wv, wv+4}; lane ln = chart s (<48)
  // dot via coalesced KALLT[k][ln]; dist2 = |z|^2 - 2 z.anc + |anc|^2 via ANCT
  {
    const float* kt = ws + OFF_KALLT + ln;
    const float* at = ws + OFF_ANCT + ln;
    float ancn = ws[OFF_ANCN + ln];
    #pragma unroll
    for (int h = 0; h < 2; ++h) {
      int bi = wv + 4 * h;
      const float* qrow = &sm[S_QFP + bi * 260];
      float dot = 0.f;
      #pragma unroll 4
      for (int k4 = 0; k4 < 64; ++k4) {
        float4 q4 = *(const float4*)&qrow[k4 * 4];
        float k0 = kt[(k4 * 4 + 0) * 48];
        float k1 = kt[(k4 * 4 + 1) * 48];
        float k2 = kt[(k4 * 4 + 2) * 48];
        float k3 = kt[(k4 * 4 + 3) * 48];
        dot += q4.x * k0 + q4.y * k1 + q4.z * k2 + q4.w * k3;
      }
      const float* zrow = &sm[S_ZS + bi * 68];
      float za = 0.f;
      #pragma unroll 4
      for (int k4 = 0; k4 < 16; ++k4) {
        float4 z4 = *(const float4*)&zrow[k4 * 4];
        float a0 = at[(k4 * 4 + 0) * 48];
        float a1 = at[(k4 * 4 + 1) * 48];
        float a2 = at[(k4 * 4 + 2) * 48];
        float a3 = at[(k4 * 4 + 3) * 48];
        za += z4.x * a0 + z4.y * a1 + z4.z * a2 + z4.w * a3;
      }
      float zn = sm[S_RED + bi * 16 + 10];
      float rwv = (ln < 16) ? sm[S_ARWS + bi * 20 + ln] : sm[S_RWS + bi * 36 + (ln - 16)];
      float sc = rwv * dot * 0.0625f - (zn - 2.f * za + ancn);
      if (ln < 48) sm[S_SW + bi * 52 + ln] = sc;
    }
  }
  __syncthreads();

  // softmax + fold routing weights: wave wv owns batches {wv, wv+4}
  {
    #pragma unroll
    for (int h = 0; h < 2; ++h) {
      int bi = wv + 4 * h;
      float* swr = &sm[S_SW + bi * 52];
      float scv = (ln < 50) ? swr[ln] : -1e30f;
      float mx = scv;
      #pragma unroll
      for (int m = 32; m >= 1; m >>= 1) mx = fmaxf(mx, __shfl_xor(mx, m, 64));
      float ev = (ln < 50) ? __expf(scv - mx) : 0.f;
      float sum = ev;
      #pragma unroll
      for (int m = 32; m >= 1; m >>= 1) sum += __shfl_xor(sum, m, 64);
      float inv = 1.f / sum;
      float fold = 1.f;
      if (ln < 16) fold = sm[S_ARWS + bi * 20 + ln];
      else if (ln < 48) fold = sm[S_RWS + bi * 36 + (ln - 16)];
      if (ln < 50) swr[ln] = ev * inv * fold;
    }
  }
  __syncthreads();

  // feat_pre column t for 8 batches -> S_QFP (overwrites q; q last read 2 syncs ago)
  {
    float acc[TB];
    #pragma unroll
    for (int bi = 0; bi < TB; ++bi)
      acc[bi] = sm[S_SW + bi * 52 + 48] * vlr[bi] + sm[S_SW + bi * 52 + 49] * vcr[bi];
    for (int sc = 0; sc < 12; ++sc) {
      float v0 = ws[OFF_VALL + (sc * 4 + 0) * 256 + t];
      float v1 = ws[OFF_VALL + (sc * 4 + 1) * 256 + t];
      float v2 = ws[OFF_VALL + (sc * 4 + 2) * 256 + t];
      float v3 = ws[OFF_VALL + (sc * 4 + 3) * 256 + t];
      #pragma unroll
      for (int bi = 0; bi < TB; ++bi) {
        float4 w4 = *(const float4*)&sm[S_SW + bi * 52 + sc * 4];
        acc[bi] += w4.x * v0 + w4.y * v1 + w4.z * v2 + w4.w * v3;
      }
    }
    #pragma unroll
    for (int bi = 0; bi < TB; ++bi) sm[S_QFP + bi * 260 + t] = acc[bi];
  }

  // g = feat_pre @ M (M staged in 64-row LDS chunks); 2 outputs/thread
  float g0 = 0.f, g1 = 0.f;
  const int d = ln;
  for (int tc = 0; tc < 4; ++tc) {
    __syncthreads();   // tc=0: also the S_QFP write->read barrier
    for (int e = t * 4; e < 4096; e += 1024) {
      int kr = e >> 6, dd = e & 63;
      *(float4*)&sm[S_MST + kr * 68 + dd] = *(const float4*)(ws + OFF_M + (tc * 64 + kr) * 64 + dd);
    }
    __syncthreads();
    #pragma unroll 4
    for (int k4 = 0; k4 < 16; ++k4) {
      float m0 = sm[S_MST + (k4 * 4 + 0) * 68 + d];
      float m1 = sm[S_MST + (k4 * 4 + 1) * 68 + d];
      float m2 = sm[S_MST + (k4 * 4 + 2) * 68 + d];
      float m3 = sm[S_MST + (k4 * 4 + 3) * 68 + d];
      float4 f0 = *(const float4*)&sm[S_QFP + wv * 260 + tc * 64 + k4 * 4];
      float4 f1 = *(const float4*)&sm[S_QFP + (wv + 4) * 260 + tc * 64 + k4 * 4];
      g0 += f0.x * m0 + f0.y * m1 + f0.z * m2 + f0.w * m3;
      g1 += f1.x * m0 + f1.y * m1 + f1.z * m2 + f1.w * m3;
    }
  }

  // epilogue: per-batch projections -> A (needs 1/sigma), B (sigma-free)
  {
    float fbv = fb[d];
    #pragma unroll
    for (int s = 0; s < 2; ++s) {
      float g = (s == 0) ? g0 : g1;
      int bi = wv + s * 4;
      int bb = b0 + bi;
      float c = ctrl[bb * 64 + d];
      float e = ecov[bb * 64 + d];
      float gc = g * c, ge = g * e, ec = e * c, ee = e * e, fc = fbv * c, fe = fbv * e;
      #pragma unroll
      for (int m = 32; m >= 1; m >>= 1) {
        gc += __shfl_xor(gc, m, 64);
        ge += __shfl_xor(ge, m, 64);
        ec += __shfl_xor(ec, m, 64);
        ee += __shfl_xor(ee, m, 64);
        fc += __shfl_xor(fc, m, 64);
        fe += __shfl_xor(fe, m, 64);
      }
      if (ln == 0) {
        float A, Bv;
        if (ee > 1e-8f) { float r = ec / ee; A = gc - ge * r; Bv = fc - fe * r; }
        else { A = gc; Bv = fc; }
        ws[OFF_A  + bb] = A;
        ws[OFF_Bc + bb] = Bv;
      }
    }
  }
}

// ===================== K3: apply 1/sigma =====================
__global__ __launch_bounds__(256)
void k3_out(const float* __restrict__ ws, float* __restrict__ out) {
  int b = blockIdx.x * 256 + threadIdx.x;
  float rs = ws[OFF_RS];
  out[b] = ws[OFF_A + b] * rs + ws[OFF_Bc + b];
}

extern "C" void kernel_launch(void* const* d_in, const int* in_sizes, int n_in,
                              void* d_out, int out_size, void* d_ws, size_t ws_size,
                              hipStream_t stream) {
  const float* z     = (const float*)d_in[0];
  const float* rw    = (const float*)d_in[1];
  const float* az    = (const float*)d_in[2];
  const float* arw   = (const float*)d_in[3];
  const float* acz   = (const float*)d_in[4];
  const float* ctrl  = (const float*)d_in[5];
  const float* ecov  = (const float*)d_in[6];
  const float* chemb = (const float*)d_in[7];
  const float* chanc = (const float*)d_in[8];
  const float* aemb  = (const float*)d_in[9];
  const float* aanc  = (const float*)d_in[10];
  const float* zW    = (const float*)d_in[11];
  const float* zb    = (const float*)d_in[12];
  const float* latW  = (const float*)d_in[13];
  const float* latb  = (const float*)d_in[14];
  const float* codeW = (const float*)d_in[15];
  const float* codeb = (const float*)d_in[16];
  const float* Wq    = (const float*)d_in[17];
  const float* Wk    = (const float*)d_in[18];
  const float* Wv    = (const float*)d_in[19];
  const float* Wo    = (const float*)d_in[20];
  const float* fW    = (const float*)d_in[21];
  const float* fb    = (const float*)d_in[22];
  float* ws  = (float*)d_ws;
  float* out = (float*)d_out;

  k1_fold<<<78, 256, 0, stream>>>(chemb, aemb, zW, zb, latW, latb, codeW, codeb,
                                  Wq, Wk, Wv, Wo, fW, aanc, chanc, ws);
  k2_main<<<513, 256, 0, stream>>>(z, rw, az, arw, acz, ctrl, ecov, fb, ws);
  k3_out<<<16, 256, 0, stream>>>(ws, out);
}

// Round 3
// 191.766 us; speedup vs baseline: 1.1827x; 1.1809x over previous
//
#include <hip/hip_runtime.h>

// B=4096, D=64, DM=256, K=32, KA=16, S=50
#define TB 8
#define HB 4            // batches per thread-half in k2 (512-thread blocks)
#define SQUARINGS 8

// ---- workspace layout (float offsets); ~559 KB ----
#define OFF_W5    0        // 5 x [64 k][256 j] folded mats (natural layout): q,klat,vlat,kcode,vcode
#define OFF_B5    81920    // 5 x [256]
#define OFF_KALLT 83200    // [256 k][48 s]  (achart rows 0..15, chart 16..47) @Wk, transposed
#define OFF_VALL  95488    // [48 s][256 j] @Wv
#define OFF_ANCT  107776   // [64 d][48 s] anchors transposed
#define OFF_ANCN  110848   // [64] |anchor_s|^2 (48 used)
#define OFF_M     110912   // [256 k][64 d]  Wo @ form_W
#define OFF_G     127296   // [64][64] form_W^T form_W
#define OFF_RS    131392   // 1/sigma (+pad)
#define OFF_A     131456   // [4096] sigma-scaled part
#define OFF_Bc    135552   // [4096] sigma-free part  (end 139648)

// ---- k2 LDS layout (floats), TB=8 ----
#define S_ZS    0         // [8][68]
#define S_AZS   544
#define S_ACZS  1088
#define S_RWS   1632      // [8][36]
#define S_ARWS  1920      // [8][20]
#define S_QFP   2080      // [8][260]  q, later feat_pre
#define S_SW    4160      // [8][52]
#define S_RED   4576      // [8][16]
#define S_MST   4704      // [64][68] M chunk stage -> ends 9056
// sigma overlay: HA=sm[0..4351], HB=sm[4352..8703], scalars 8704..8771
#define SIG_HB  4352
#define SIG_SC  8704
#define SIG_V   8708
#define SMEM_K2 9056      // 36.2 KB -> 2 blocks/CU at 512 threads

// ===================== K1: weight folds, 2005 light blocks (proven structure) =====================
// b<1300: W5 natural + B5; 1300..1683: KALLT/VALL; 1684..1939: M; 1940..2003: G; 2004: ANCT/ANCN
__global__ __launch_bounds__(256)
void k1_fold(const float* __restrict__ chart_emb, const float* __restrict__ a_chart_emb,
             const float* __restrict__ zW, const float* __restrict__ zb,
             const float* __restrict__ latW, const float* __restrict__ latb,
             const float* __restrict__ codeW, const float* __restrict__ codeb,
             const float* __restrict__ Wq, const float* __restrict__ Wk,
             const float* __restrict__ Wv, const float* __restrict__ Wo,
             const float* __restrict__ fW, const float* __restrict__ ach_anchor,
             const float* __restrict__ ch_anchor, float* __restrict__ ws) {
  __shared__ float red[256];
  const int t = threadIdx.x;
  const int b = blockIdx.x;

  if (b == 2004) {   // anchors: ANCT (transposed) + ANCN (|anchor|^2)
    for (int e = t; e < 3072; e += 256) {
      int s = e >> 6, d = e & 63;
      float v = (s < 16) ? ach_anchor[s * 64 + d] : ch_anchor[(s - 16) * 64 + d];
      ws[OFF_ANCT + d * 48 + s] = v;
    }
    if (t < 64) {
      float n = 0.f;
      if (t < 48) {
        const float* a = (t < 16) ? (ach_anchor + t * 64) : (ch_anchor + (t - 16) * 64);
        #pragma unroll 4
        for (int d = 0; d < 64; ++d) n += a[d] * a[d];
      }
      ws[OFF_ANCN + t] = n;
    }
    return;
  }

  const float* Arow; const float* Bm;
  int astride = 1, bstride = 256, jbase = 0, dstBase, dstStride = 1;
  if (b < 1300) {                       // W5 (natural layout) + biases
    int u = b / 260, r = b - u * 260;
    int i = r >> 2, jc = r & 3; jbase = jc * 64;
    const float* Amat = (u == 0) ? zW : (u <= 2 ? latW : codeW);
    const float* bias = (u == 0) ? zb : (u <= 2 ? latb : codeb);
    Bm = (u == 0) ? Wq : ((u == 1 || u == 3) ? Wk : Wv);
    if (i < 64) {
      Arow = Amat + i * 256;
      dstBase = OFF_W5 + u * 16384 + i * 256 + jbase;   // row i, cols jbase..+63
    } else {
      Arow = bias;
      dstBase = OFF_B5 + u * 256 + jbase;
    }
  } else if (b < 1684) {                // KALLT (transposed store) / VALL
    int rr = b - 1300; int row = rr >> 2, jc = rr & 3; jbase = jc * 64;
    int s = (row < 48) ? row : row - 48;
    Bm = (row < 48) ? Wk : Wv;
    Arow = (s < 16) ? (a_chart_emb + s * 256) : (chart_emb + (s - 16) * 256);
    if (row < 48) { dstBase = OFF_KALLT + jbase * 48 + row; dstStride = 48; }
    else          { dstBase = OFF_VALL + (row - 48) * 256 + jbase; }
  } else if (b < 1940) {                // M
    int i = b - 1684;
    Arow = Wo + i * 256; Bm = fW; bstride = 64;
    dstBase = OFF_M + i * 64;
  } else {                              // G
    int i = b - 1940;
    Arow = fW + i; astride = 64; Bm = fW; bstride = 64;
    dstBase = OFF_G + i * 64;
  }

  const int j = t & 63, ks = t >> 6;
  const float* ap = Arow + (ks * 64) * astride;
  const float* bp = Bm + (ks * 64) * bstride + jbase + j;
  float a0 = 0.f, a1 = 0.f, a2 = 0.f, a3 = 0.f;
  #pragma unroll 4
  for (int k = 0; k < 64; k += 4) {
    a0 += ap[(k + 0) * astride] * bp[(k + 0) * bstride];
    a1 += ap[(k + 1) * astride] * bp[(k + 1) * bstride];
    a2 += ap[(k + 2) * astride] * bp[(k + 2) * bstride];
    a3 += ap[(k + 3) * astride] * bp[(k + 3) * bstride];
  }
  red[t] = (a0 + a1) + (a2 + a3);
  __syncthreads();
  if (t < 64) {
    float v = red[t] + red[64 + t] + red[128 + t] + red[192 + t];
    ws[dstBase + t * dstStride] = v;
  }
}

// coalesced matvec: r[bi] = bias[tt] + sum_k x[bi][k] * W5[u][k][tt]
__device__ __forceinline__ void mv(const float* __restrict__ ws, int u,
                                   const float* xs, int tt, float* r) {
  const float* w = ws + OFF_W5 + u * 16384 + tt;
  float bq = ws[OFF_B5 + u * 256 + tt];
  #pragma unroll
  for (int bi = 0; bi < HB; ++bi) r[bi] = bq;
  #pragma unroll 4
  for (int k4 = 0; k4 < 16; ++k4) {
    float w0 = w[(k4 * 4 + 0) * 256];
    float w1 = w[(k4 * 4 + 1) * 256];
    float w2 = w[(k4 * 4 + 2) * 256];
    float w3 = w[(k4 * 4 + 3) * 256];
    #pragma unroll
    for (int bi = 0; bi < HB; ++bi) {
      float4 x4 = *(const float4*)&xs[bi * 68 + k4 * 4];
      r[bi] += x4.x * w0 + x4.y * w1 + x4.z * w2 + x4.w * w3;
    }
  }
}

// ===================== K2: 512-thread blocks, 8 batches, wave-per-batch phases =====================
__global__ __launch_bounds__(512, 4)
void k2_main(const float* __restrict__ z, const float* __restrict__ rw,
             const float* __restrict__ az, const float* __restrict__ arw,
             const float* __restrict__ acz, const float* __restrict__ ctrl,
             const float* __restrict__ ecov, const float* __restrict__ fb,
             float* __restrict__ ws) {
  __shared__ __align__(16) float sm[SMEM_K2];
  const int t = threadIdx.x;
  const int wv = t >> 6, ln = t & 63;
  const int half = t >> 8, tt = t & 255;
  const int hb0 = half * 4;            // first batch of this thread-half

  if (blockIdx.x == 512) {
    // ---------- sigma: 8 trace-normalized squarings of G, Rayleigh on global G (512 threads) ----------
    float* HA = sm;
    float* HBUF = sm + SIG_HB;
    {
      float tv = (t < 64) ? ws[OFF_G + t * 65] : 0.f;
      #pragma unroll
      for (int m = 32; m >= 1; m >>= 1) tv += __shfl_xor(tv, m, 64);
      if (t == 0) sm[SIG_SC] = (tv > 0.f) ? 1.f / tv : 0.f;
    }
    __syncthreads();
    {
      float inv0 = sm[SIG_SC];
      for (int e = t; e < 4096; e += 512) {
        int i = e >> 6, j = e & 63;
        HA[i * 68 + j] = ws[OFF_G + e] * inv0;
      }
    }
    __syncthreads();
    for (int it = 0; it < SQUARINGS; ++it) {
      float* src = (it & 1) ? HBUF : HA;
      float* dst = (it & 1) ? HA : HBUF;
      float acc8[8];
      #pragma unroll
      for (int r = 0; r < 8; ++r) acc8[r] = 0.f;
      for (int hh = 0; hh < 2; ++hh) {        // 32-wide column cache halves
        float cb[32];
        #pragma unroll
        for (int k = 0; k < 32; ++k) cb[k] = src[(hh * 32 + k) * 68 + ln];
        #pragma unroll
        for (int r = 0; r < 8; ++r) {
          int i = r * 8 + wv;
          float a = 0.f;
          #pragma unroll
          for (int k4 = 0; k4 < 8; ++k4) {
            float4 a4 = *(const float4*)&src[i * 68 + hh * 32 + k4 * 4];
            a += a4.x * cb[k4 * 4] + a4.y * cb[k4 * 4 + 1] + a4.z * cb[k4 * 4 + 2] + a4.w * cb[k4 * 4 + 3];
          }
          acc8[r] += a;
        }
      }
      #pragma unroll
      for (int r = 0; r < 8; ++r) dst[(r * 8 + wv) * 68 + ln] = acc8[r];
      __syncthreads();
      {
        float tv = (t < 64) ? dst[t * 68 + t] : 0.f;
        #pragma unroll
        for (int m = 32; m >= 1; m >>= 1) tv += __shfl_xor(tv, m, 64);
        if (t == 0) sm[SIG_SC] = (tv > 0.f) ? 1.f / tv : 0.f;
      }
      __syncthreads();
      {
        float sc = sm[SIG_SC];
        #pragma unroll
        for (int r = 0; r < 8; ++r) dst[(r * 8 + wv) * 68 + ln] *= sc;
      }
      __syncthreads();
    }
    float* H = (SQUARINGS & 1) ? HBUF : HA;
    if (t < 64) {
      float cn = 0.f;
      for (int i = 0; i < 64; ++i) { float h = H[i * 68 + t]; cn += h * h; }
      float bv = cn; int bj = t;
      #pragma unroll
      for (int m = 32; m >= 1; m >>= 1) {
        float ov = __shfl_xor(bv, m, 64);
        int   oj = __shfl_xor(bj, m, 64);
        if (ov > bv || (ov == bv && oj < bj)) { bv = ov; bj = oj; }
      }
      if (t == 0) sm[SIG_SC + 1] = (float)bj;
    }
    __syncthreads();
    {
      int jmax = (int)sm[SIG_SC + 1];
      if (t < 64) sm[SIG_V + t] = H[t * 68 + jmax];
    }
    __syncthreads();
    if (t < 64) {
      float vi = sm[SIG_V + t];
      float y = 0.f;
      #pragma unroll 4
      for (int k = 0; k < 64; ++k) y += ws[OFF_G + t * 64 + k] * sm[SIG_V + k];
      float num = vi * y, den = vi * vi;
      #pragma unroll
      for (int m = 32; m >= 1; m >>= 1) {
        num += __shfl_xor(num, m, 64);
        den += __shfl_xor(den, m, 64);
      }
      if (t == 0) {
        float lam = (den > 1e-37f) ? num / den : 0.f;
        lam = fmaxf(lam, 0.f);
        float sg = sqrtf(lam);
        ws[OFF_RS] = 1.f / fmaxf(sg, 1e-8f);
      }
    }
    return;
  }

  // ---------- main: 512 blocks x 8 batches, wave wv owns batch wv for per-batch phases ----------
  const int b0 = blockIdx.x * TB;
  {
    int bb = b0 + wv;                       // one batch row per wave, coalesced 256B
    sm[S_ZS   + wv * 68 + ln] = z[bb * 64 + ln];
    sm[S_AZS  + wv * 68 + ln] = az[bb * 64 + ln];
    sm[S_ACZS + wv * 68 + ln] = acz[bb * 64 + ln];
  }
  if (t < 256) { int bi = t >> 5, d = t & 31; sm[S_RWS + bi * 36 + d] = rw[(b0 + bi) * 32 + d]; }
  else if (t < 384) { int t2 = t - 256; int bi = t2 >> 4, d = t2 & 15; sm[S_ARWS + bi * 20 + d] = arw[(b0 + bi) * 16 + d]; }
  __syncthreads();

  // --- q (kept live briefly), k_lat / k_code consumed immediately ---
  float qr[HB];
  mv(ws, 0, sm + S_ZS + hb0 * 68, tt, qr);
  #pragma unroll
  for (int bi = 0; bi < HB; ++bi) sm[S_QFP + (hb0 + bi) * 260 + tt] = qr[bi];
  {
    float kr[HB];
    mv(ws, 1, sm + S_AZS + hb0 * 68, tt, kr);
    #pragma unroll
    for (int bi = 0; bi < HB; ++bi) {
      float p = qr[bi] * kr[bi];
      #pragma unroll
      for (int m = 32; m >= 1; m >>= 1) p += __shfl_xor(p, m, 64);
      if (ln == 0) sm[S_RED + (hb0 + bi) * 16 + (wv & 3)] = p;
    }
  }
  {
    float kr[HB];
    mv(ws, 3, sm + S_ACZS + hb0 * 68, tt, kr);
    #pragma unroll
    for (int bi = 0; bi < HB; ++bi) {
      float p = qr[bi] * kr[bi];
      #pragma unroll
      for (int m = 32; m >= 1; m >>= 1) p += __shfl_xor(p, m, 64);
      if (ln == 0) sm[S_RED + (hb0 + bi) * 16 + 4 + (wv & 3)] = p;
    }
  }
  {
    // lat/code latent distances + |z|^2: wave wv owns batch wv
    float zv = sm[S_ZS + wv * 68 + ln];
    float a = zv - sm[S_AZS + wv * 68 + ln];
    float c = zv - sm[S_ACZS + wv * 68 + ln];
    float dL = a * a, dC = c * c, zz = zv * zv;
    #pragma unroll
    for (int m = 32; m >= 1; m >>= 1) {
      dL += __shfl_xor(dL, m, 64);
      dC += __shfl_xor(dC, m, 64);
      zz += __shfl_xor(zz, m, 64);
    }
    if (ln == 0) {
      sm[S_RED + wv * 16 + 8]  = dL;
      sm[S_RED + wv * 16 + 9]  = dC;
      sm[S_RED + wv * 16 + 10] = zz;
    }
  }
  // --- v_lat / v_code, kept in regs until feat_pre ---
  float vlr[HB], vcr[HB];
  mv(ws, 2, sm + S_AZS + hb0 * 68, tt, vlr);
  mv(ws, 4, sm + S_ACZS + hb0 * 68, tt, vcr);
  __syncthreads();

  if (t < TB) {
    float pL = sm[S_RED + t * 16 + 0] + sm[S_RED + t * 16 + 1] + sm[S_RED + t * 16 + 2] + sm[S_RED + t * 16 + 3];
    float pC = sm[S_RED + t * 16 + 4] + sm[S_RED + t * 16 + 5] + sm[S_RED + t * 16 + 6] + sm[S_RED + t * 16 + 7];
    sm[S_SW + t * 52 + 48] = pL * 0.0625f - sm[S_RED + t * 16 + 8];
    sm[S_SW + t * 52 + 49] = pC * 0.0625f - sm[S_RED + t * 16 + 9];
  }

  // chart scores: wave wv handles batch wv; lane ln = chart s (<48)
  {
    const float* kt = ws + OFF_KALLT + ln;
    const float* at = ws + OFF_ANCT + ln;
    float ancn = ws[OFF_ANCN + ln];
    const float* qrow = &sm[S_QFP + wv * 260];
    float dot = 0.f;
    #pragma unroll 4
    for (int k4 = 0; k4 < 64; ++k4) {
      float4 q4 = *(const float4*)&qrow[k4 * 4];
      float k0 = kt[(k4 * 4 + 0) * 48];
      float k1 = kt[(k4 * 4 + 1) * 48];
      float k2 = kt[(k4 * 4 + 2) * 48];
      float k3 = kt[(k4 * 4 + 3) * 48];
      dot += q4.x * k0 + q4.y * k1 + q4.z * k2 + q4.w * k3;
    }
    const float* zrow = &sm[S_ZS + wv * 68];
    float za = 0.f;
    #pragma unroll 4
    for (int k4 = 0; k4 < 16; ++k4) {
      float4 z4 = *(const float4*)&zrow[k4 * 4];
      float a0 = at[(k4 * 4 + 0) * 48];
      float a1 = at[(k4 * 4 + 1) * 48];
      float a2 = at[(k4 * 4 + 2) * 48];
      float a3 = at[(k4 * 4 + 3) * 48];
      za += z4.x * a0 + z4.y * a1 + z4.z * a2 + z4.w * a3;
    }
    float zn = sm[S_RED + wv * 16 + 10];
    float rwv = (ln < 16) ? sm[S_ARWS + wv * 20 + ln] : sm[S_RWS + wv * 36 + (ln - 16)];
    float sc = rwv * dot * 0.0625f - (zn - 2.f * za + ancn);
    if (ln < 48) sm[S_SW + wv * 52 + ln] = sc;
  }
  __syncthreads();

  // softmax + fold routing weights: wave wv owns batch wv
  {
    float* swr = &sm[S_SW + wv * 52];
    float scv = (ln < 50) ? swr[ln] : -1e30f;
    float mx = scv;
    #pragma unroll
    for (int m = 32; m >= 1; m >>= 1) mx = fmaxf(mx, __shfl_xor(mx, m, 64));
    float ev = (ln < 50) ? __expf(scv - mx) : 0.f;
    float sum = ev;
    #pragma unroll
    for (int m = 32; m >= 1; m >>= 1) sum += __shfl_xor(sum, m, 64);
    float inv = 1.f / sum;
    float fold = 1.f;
    if (ln < 16) fold = sm[S_ARWS + wv * 20 + ln];
    else if (ln < 48) fold = sm[S_RWS + wv * 36 + (ln - 16)];
    if (ln < 50) swr[ln] = ev * inv * fold;
  }
  __syncthreads();

  // feat_pre column tt for this half's 4 batches -> S_QFP (overwrites q; q last read before prev barrier)
  {
    float acc[HB];
    #pragma unroll
    for (int bi = 0; bi < HB; ++bi)
      acc[bi] = sm[S_SW + (hb0 + bi) * 52 + 48] * vlr[bi] + sm[S_SW + (hb0 + bi) * 52 + 49] * vcr[bi];
    for (int sc = 0; sc < 12; ++sc) {
      float v0 = ws[OFF_VALL + (sc * 4 + 0) * 256 + tt];
      float v1 = ws[OFF_VALL + (sc * 4 + 1) * 256 + tt];
      float v2 = ws[OFF_VALL + (sc * 4 + 2) * 256 + tt];
      float v3 = ws[OFF_VALL + (sc * 4 + 3) * 256 + tt];
      #pragma unroll
      for (int bi = 0; bi < HB; ++bi) {
        float4 w4 = *(const float4*)&sm[S_SW + (hb0 + bi) * 52 + sc * 4];
        acc[bi] += w4.x * v0 + w4.y * v1 + w4.z * v2 + w4.w * v3;
      }
    }
    #pragma unroll
    for (int bi = 0; bi < HB; ++bi) sm[S_QFP + (hb0 + bi) * 260 + tt] = acc[bi];
  }

  // g = feat_pre @ M (M staged in 64-row LDS chunks); wave wv -> batch wv, dim ln
  float g0 = 0.f;
  const int d = ln;
  for (int tc = 0; tc < 4; ++tc) {
    __syncthreads();   // tc=0: also the S_QFP write->read barrier
    for (int e = t * 4; e < 4096; e += 2048) {
      int kr = e >> 6, dd = e & 63;
      *(float4*)&sm[S_MST + kr * 68 + dd] = *(const float4*)(ws + OFF_M + (tc * 64 + kr) * 64 + dd);
    }
    __syncthreads();
    #pragma unroll 4
    for (int k4 = 0; k4 < 16; ++k4) {
      float m0 = sm[S_MST + (k4 * 4 + 0) * 68 + d];
      float m1 = sm[S_MST + (k4 * 4 + 1) * 68 + d];
      float m2 = sm[S_MST + (k4 * 4 + 2) * 68 + d];
      float m3 = sm[S_MST + (k4 * 4 + 3) * 68 + d];
      float4 f0 = *(const float4*)&sm[S_QFP + wv * 260 + tc * 64 + k4 * 4];  // wave-uniform broadcast
      g0 += f0.x * m0 + f0.y * m1 + f0.z * m2 + f0.w * m3;
    }
  }

  // epilogue: wave wv -> batch wv projections -> A (needs 1/sigma), B (sigma-free)
  {
    float fbv = fb[d];
    int bb = b0 + wv;
    float c = ctrl[bb * 64 + d];
    float e = ecov[bb * 64 + d];
    float gc = g0 * c, ge = g0 * e, ec = e * c, ee = e * e, fc = fbv * c, fe = fbv * e;
    #pragma unroll
    for (int m = 32; m >= 1; m >>= 1) {
      gc += __shfl_xor(gc, m, 64);
      ge += __shfl_xor(ge, m, 64);
      ec += __shfl_xor(ec, m, 64);
      ee += __shfl_xor(ee, m, 64);
      fc += __shfl_xor(fc, m, 64);
      fe += __shfl_xor(fe, m, 64);
    }
    if (ln == 0) {
      float A, Bv;
      if (ee > 1e-8f) { float r = ec / ee; A = gc - ge * r; Bv = fc - fe * r; }
      else { A = gc; Bv = fc; }
      ws[OFF_A  + bb] = A;
      ws[OFF_Bc + bb] = Bv;
    }
  }
}

// ===================== K3: apply 1/sigma =====================
__global__ __launch_bounds__(256)
void k3_out(const float* __restrict__ ws, float* __restrict__ out) {
  int b = blockIdx.x * 256 + threadIdx.x;
  float rs = ws[OFF_RS];
  out[b] = ws[OFF_A + b] * rs + ws[OFF_Bc + b];
}

extern "C" void kernel_launch(void* const* d_in, const int* in_sizes, int n_in,
                              void* d_out, int out_size, void* d_ws, size_t ws_size,
                              hipStream_t stream) {
  const float* z     = (const float*)d_in[0];
  const float* rw    = (const float*)d_in[1];
  const float* az    = (const float*)d_in[2];
  const float* arw   = (const float*)d_in[3];
  const float* acz   = (const float*)d_in[4];
  const float* ctrl  = (const float*)d_in[5];
  const float* ecov  = (const float*)d_in[6];
  const float* chemb = (const float*)d_in[7];
  const float* chanc = (const float*)d_in[8];
  const float* aemb  = (const float*)d_in[9];
  const float* aanc  = (const float*)d_in[10];
  const float* zW    = (const float*)d_in[11];
  const float* zb    = (const float*)d_in[12];
  const float* latW  = (const float*)d_in[13];
  const float* latb  = (const float*)d_in[14];
  const float* codeW = (const float*)d_in[15];
  const float* codeb = (const float*)d_in[16];
  const float* Wq    = (const float*)d_in[17];
  const float* Wk    = (const float*)d_in[18];
  const float* Wv    = (const float*)d_in[19];
  const float* Wo    = (const float*)d_in[20];
  const float* fW    = (const float*)d_in[21];
  const float* fb    = (const float*)d_in[22];
  float* ws  = (float*)d_ws;
  float* out = (float*)d_out;

  k1_fold<<<2005, 256, 0, stream>>>(chemb, aemb, zW, zb, latW, latb, codeW, codeb,
                                    Wq, Wk, Wv, Wo, fW, aanc, chanc, ws);
  k2_main<<<513, 512, 0, stream>>>(z, rw, az, arw, acz, ctrl, ecov, fb, ws);
  k3_out<<<16, 256, 0, stream>>>(ws, out);
}